// Round 12
// baseline (222.411 us; speedup 1.0000x reference)
//
#include <hip/hip_runtime.h>
#include <hip/hip_bf16.h>

// Problem shapes (fixed by setup_inputs):
//   b=2, L=1024, d_model=1024, d_inner=2048, d_state=16, D_CONV=4
#define NTOK   2048
#define DMODEL 1024
#define DINNER 2048
#define DSTATE 16
#define SEQLEN 1024
#define NPROJ  33   // 2*d_state + 1
#define NPAD   48   // NPROJ padded for MFMA tiles
#define PSTRIDE 36  // proj row stride (16B-aligned, cols 33..35 = 0)
#define CCH    64   // scan chunks per sequence
#define CT     16   // steps per chunk

typedef __attribute__((ext_vector_type(8))) short bf16x8;
typedef __attribute__((ext_vector_type(4))) float f32x4;
typedef __attribute__((ext_vector_type(8))) unsigned short us8;

__device__ __forceinline__ unsigned short f2bf(float f) {
  unsigned u = __float_as_uint(f);
  return (unsigned short)((u + 0x7FFFu + ((u >> 16) & 1u)) >> 16);  // RNE
}
__device__ __forceinline__ float bf2f(unsigned short u) {
  return __uint_as_float(((unsigned)u) << 16);
}

__device__ __forceinline__ void gload_lds16(const void* g, void* l) {
  __builtin_amdgcn_global_load_lds(
      (const __attribute__((address_space(1))) unsigned int*)g,
      (__attribute__((address_space(3))) unsigned int*)l, 16, 0, 0);
}

// ---------------------------------------------------------------------------
// Fused fp32->bf16 cast: x (2M) | in_w (4M) | xproj_w padded to 48x2048.
// Blocks 0..35 additionally zero proj36 (2048 x 36 floats) for conv_xproj's
// atomicAdd epilogue.
// ---------------------------------------------------------------------------
#define CAST_N0 (NTOK * DMODEL)                       // 2097152
#define CAST_N1 (CAST_N0 + 2 * DINNER * DMODEL)       // 6291456
#define CAST_N2 (CAST_N1 + NPAD * DINNER)             // 6389760
__global__ __launch_bounds__(256) void cast3_bf16_kernel(
    const float* __restrict__ s0, const float* __restrict__ s1,
    const float* __restrict__ s3, unsigned short* __restrict__ dst,
    float* __restrict__ proj) {
  if (blockIdx.x < 36) {
    const int o = blockIdx.x * 2048 + threadIdx.x * 8;
    const float4 z4 = make_float4(0.f, 0.f, 0.f, 0.f);
    *(float4*)(proj + o) = z4;
    *(float4*)(proj + o + 4) = z4;
  }
  const int idx = (blockIdx.x * 256 + threadIdx.x) * 8;
  const float* src;
  int off;
  if (idx < CAST_N0) { src = s0; off = idx; }
  else if (idx < CAST_N1) { src = s1; off = idx - CAST_N0; }
  else {
    off = idx - CAST_N1;
    if (off >= NPROJ * DINNER) {  // zero pad rows 33..47
      us8 z = {0, 0, 0, 0, 0, 0, 0, 0};
      *(us8*)(dst + idx) = z;
      return;
    }
    src = s3;
  }
  const float4 a = *(const float4*)(src + off);
  const float4 b = *(const float4*)(src + off + 4);
  us8 o;
  o[0] = f2bf(a.x); o[1] = f2bf(a.y); o[2] = f2bf(a.z); o[3] = f2bf(a.w);
  o[4] = f2bf(b.x); o[5] = f2bf(b.y); o[6] = f2bf(b.z); o[7] = f2bf(b.w);
  *(us8*)(dst + idx) = o;
}

// ---------------------------------------------------------------------------
// bf16 MFMA GEMM (gemm1): C_bf16[n,m] = f2bf(sum_k A[n,k]*B[m,k] + bias[m]).
// Block tile 128x128; K advances 64 per barrier pair (two 32-deep stages).
// ---------------------------------------------------------------------------
__global__ __launch_bounds__(256) void gemm_bt_mfma(
    const unsigned short* __restrict__ A, const unsigned short* __restrict__ B,
    const float* __restrict__ bias, unsigned short* __restrict__ C,
    int M, int K) {
  constexpr int BN = 128, TN = 4;
  __shared__ unsigned short As[2][128 * 32];
  __shared__ unsigned short Bs[2][BN * 32];

  const int tid = threadIdx.x;
  const int wid = tid >> 6;
  const int lane = tid & 63;
  const int n0 = blockIdx.x * 128;
  const int m0 = blockIdx.y * BN;

  const int wave_m = wid & 1;
  const int wave_n = wid >> 1;
  const int lm = lane & 15;
  const int lq = lane >> 4;

  f32x4 acc[4][TN] = {};

  for (int k0 = 0; k0 < K; k0 += 64) {
    __syncthreads();
#pragma unroll
    for (int h = 0; h < 2; ++h) {
      const int kh = k0 + h * 32;
#pragma unroll
      for (int j = 0; j < 2; ++j) {
        const int cb = j * 256 + wid * 64;
        const int c = cb + lane;
        gload_lds16(A + (size_t)(n0 + (c >> 2)) * K + kh + (c & 3) * 8,
                    &As[h][cb * 8]);
      }
#pragma unroll
      for (int j = 0; j < BN / 64; ++j) {
        const int cb = j * 256 + wid * 64;
        const int c = cb + lane;
        gload_lds16(B + (size_t)(m0 + (c >> 2)) * K + kh + (c & 3) * 8,
                    &Bs[h][cb * 8]);
      }
    }
    __syncthreads();

#pragma unroll
    for (int h = 0; h < 2; ++h) {
      bf16x8 af[4], bfr[TN];
#pragma unroll
      for (int tm = 0; tm < 4; ++tm)
        af[tm] = *(const bf16x8*)
            &As[h][(wave_m * 64 + tm * 16 + lm) * 32 + lq * 8];
#pragma unroll
      for (int tn = 0; tn < TN; ++tn)
        bfr[tn] = *(const bf16x8*)
            &Bs[h][(wave_n * (BN / 2) + tn * 16 + lm) * 32 + lq * 8];
#pragma unroll
      for (int tm = 0; tm < 4; ++tm)
#pragma unroll
        for (int tn = 0; tn < TN; ++tn)
          acc[tm][tn] = __builtin_amdgcn_mfma_f32_16x16x32_bf16(
              af[tm], bfr[tn], acc[tm][tn], 0, 0, 0);
    }
  }

#pragma unroll
  for (int tm = 0; tm < 4; ++tm) {
    const int row = n0 + wave_m * 64 + tm * 16 + lq * 4;
#pragma unroll
    for (int tn = 0; tn < TN; ++tn) {
      const int col = m0 + wave_n * (BN / 2) + tn * 16 + lm;
      const float bv = bias[col];
#pragma unroll
      for (int r = 0; r < 4; ++r)
        C[(size_t)(row + r) * M + col] = f2bf(acc[tm][tn][r] + bv);
    }
  }
}

// ---------------------------------------------------------------------------
// gemm2 with split-K=2 and atomicAdd epilogue (out zeroed by scan_fused).
// Block tile 128x64; grid (16, 16, 2).
// ---------------------------------------------------------------------------
__global__ __launch_bounds__(256) void gemm_bt_mfma_sk(
    const unsigned short* __restrict__ A, const unsigned short* __restrict__ B,
    float* __restrict__ C, int M, int K) {
  constexpr int BN = 64, TN = 2;
  __shared__ unsigned short As[2][128 * 32];
  __shared__ unsigned short Bs[2][BN * 32];

  const int tid = threadIdx.x;
  const int wid = tid >> 6;
  const int lane = tid & 63;
  const int n0 = blockIdx.x * 128;
  const int m0 = blockIdx.y * BN;
  const int kstart = blockIdx.z * (K >> 1);

  const int wave_m = wid & 1;
  const int wave_n = wid >> 1;
  const int lm = lane & 15;
  const int lq = lane >> 4;

  f32x4 acc[4][TN] = {};

  for (int k0 = kstart; k0 < kstart + (K >> 1); k0 += 64) {
    __syncthreads();
#pragma unroll
    for (int h = 0; h < 2; ++h) {
      const int kh = k0 + h * 32;
#pragma unroll
      for (int j = 0; j < 2; ++j) {
        const int cb = j * 256 + wid * 64;
        const int c = cb + lane;
        gload_lds16(A + (size_t)(n0 + (c >> 2)) * K + kh + (c & 3) * 8,
                    &As[h][cb * 8]);
      }
      {
        const int cb = wid * 64;
        const int c = cb + lane;
        gload_lds16(B + (size_t)(m0 + (c >> 2)) * K + kh + (c & 3) * 8,
                    &Bs[h][cb * 8]);
      }
    }
    __syncthreads();

#pragma unroll
    for (int h = 0; h < 2; ++h) {
      bf16x8 af[4], bfr[TN];
#pragma unroll
      for (int tm = 0; tm < 4; ++tm)
        af[tm] = *(const bf16x8*)
            &As[h][(wave_m * 64 + tm * 16 + lm) * 32 + lq * 8];
#pragma unroll
      for (int tn = 0; tn < TN; ++tn)
        bfr[tn] = *(const bf16x8*)
            &Bs[h][(wave_n * (BN / 2) + tn * 16 + lm) * 32 + lq * 8];
#pragma unroll
      for (int tm = 0; tm < 4; ++tm)
#pragma unroll
        for (int tn = 0; tn < TN; ++tn)
          acc[tm][tn] = __builtin_amdgcn_mfma_f32_16x16x32_bf16(
              af[tm], bfr[tn], acc[tm][tn], 0, 0, 0);
    }
  }

#pragma unroll
  for (int tm = 0; tm < 4; ++tm) {
    const int row = n0 + wave_m * 64 + tm * 16 + lq * 4;
#pragma unroll
    for (int tn = 0; tn < TN; ++tn) {
      const int col = m0 + wave_n * (BN / 2) + tn * 16 + lm;
#pragma unroll
      for (int r = 0; r < 4; ++r)
        atomicAdd(&C[(size_t)(row + r) * M + col], acc[tm][tn][r]);
    }
  }
}

// ---------------------------------------------------------------------------
// Fused depthwise conv(4) + SiLU gate + xproj MFMA with k-split atomics.
// xz is bf16. Grid (NTOK/64, DINNER/128) = 512 blocks.
// proj rows have stride PSTRIDE=36 (padded for the scan's float4 loads).
// ---------------------------------------------------------------------------
__global__ __launch_bounds__(256) void conv_xproj_mfma(
    const unsigned short* __restrict__ xz, const float* __restrict__ cw,
    const float* __restrict__ cb, const unsigned short* __restrict__ wp,
    float* __restrict__ xg, float* __restrict__ proj) {
  __shared__ unsigned short As[4][64 * 32];
  __shared__ unsigned short Bs[4][NPAD * 32];

  const int tid = threadIdx.x;
  const int wid = tid >> 6;
  const int lane = tid & 63;
  const int n0 = blockIdx.x * 64;    // token tile
  const int kb = blockIdx.y * 128;   // channel (k) tile

  // Phase A: B-tile staging, 768 x 16B chunks, stage-major dest.
#pragma unroll
  for (int j = 0; j < 3; ++j) {
    const int cbase = j * 256 + wid * 64;  // wave-uniform
    const int c = cbase + lane;
    const int stage = c / 192;
    const int rem = c - stage * 192;
    gload_lds16(wp + (size_t)(rem >> 2) * DINNER + kb + stage * 32 + (rem & 3) * 8,
                &Bs[0][0] + cbase * 8);
  }

  // Phase B: conv + SiLU. thread = chan c128, 32-token half.
  const int c128 = tid & 127;
  const int half = tid >> 7;
  const int i = kb + c128;
  const int gt0 = n0 + half * 32;
  const float4 w4 = ((const float4*)cw)[i];
  const float cbv = cb[i];

  const bool seq_start = ((gt0 & (SEQLEN - 1)) == 0);
  float tm3 = seq_start ? 0.f : bf2f(xz[(size_t)(gt0 - 3) * (2 * DINNER) + i]);
  float tm2 = seq_start ? 0.f : bf2f(xz[(size_t)(gt0 - 2) * (2 * DINNER) + i]);
  float tm1 = seq_start ? 0.f : bf2f(xz[(size_t)(gt0 - 1) * (2 * DINNER) + i]);

  unsigned short* Arow = &As[c128 >> 5][c128 & 31];
#pragma unroll 4
  for (int t = 0; t < 32; ++t) {
    const int n = gt0 + t;
    const float x0 = bf2f(xz[(size_t)n * (2 * DINNER) + i]);
    float acc = cbv;
    acc = fmaf(w4.x, tm3, acc);
    acc = fmaf(w4.y, tm2, acc);
    acc = fmaf(w4.z, tm1, acc);
    acc = fmaf(w4.w, x0, acc);
    const float z = bf2f(xz[(size_t)n * (2 * DINNER) + DINNER + i]);
    const float sig = 1.f / (1.f + __expf(-z));
    const float v = acc * (z * sig);
    xg[(size_t)n * DINNER + i] = v;
    Arow[(half * 32 + t) * 32] = f2bf(v);
    tm3 = tm2; tm2 = tm1; tm1 = x0;
  }
  __syncthreads();  // drains Bs vmcnt + As writes

  // Phase C: wave = tokens [wid*16, wid*16+16) x feats [0,48).
  const int lm = lane & 15;
  const int lq = lane >> 4;
  f32x4 acc[3] = {};
#pragma unroll
  for (int stage = 0; stage < 4; ++stage) {
    bf16x8 af = *(const bf16x8*)&As[stage][(wid * 16 + lm) * 32 + lq * 8];
#pragma unroll
    for (int tn = 0; tn < 3; ++tn) {
      bf16x8 bfr = *(const bf16x8*)&Bs[stage][(tn * 16 + lm) * 32 + lq * 8];
      acc[tn] = __builtin_amdgcn_mfma_f32_16x16x32_bf16(af, bfr, acc[tn], 0, 0, 0);
    }
  }

  const int row = n0 + wid * 16 + lq * 4;
#pragma unroll
  for (int tn = 0; tn < 3; ++tn) {
    const int col = tn * 16 + lm;
    if (col < NPROJ) {
#pragma unroll
      for (int r = 0; r < 4; ++r)
        atomicAdd(&proj[(size_t)(row + r) * PSTRIDE + col], acc[tn][r]);
    }
  }
}

// ---------------------------------------------------------------------------
// Fully fused chunked selective scan — one kernel, block-local sync only.
// Block = (batch, 4 channels); 256 threads = 4 chans x 64 chunks.
//   Phase 1: thread (c,k) scans chunk k (16 steps) from h=0 -> Hl/Sl in LDS.
//   Phase 2: 64 threads (c,s) compose 64 chunks serially in LDS (h0 prefix);
//            remaining 192 threads zero `out` and cast out_w -> bf16.
//   Phase 3: thread (c,k) re-scans seeded with h0, emits y (bf16).
// delta = 1+exp(u) == exp(softplus(u)); chunk decay exp(Av*sum(delta)).
// Grid (DINNER/4, 2) = 1024 blocks = 4/CU.
// ---------------------------------------------------------------------------
__global__ __launch_bounds__(256) void scan_fused(
    const float* __restrict__ xg, const float* __restrict__ proj,
    const float* __restrict__ dt_w, const float* __restrict__ dt_b,
    const float* __restrict__ A_log, const float* __restrict__ Dp,
    float* __restrict__ out, const float* __restrict__ out_w,
    unsigned short* __restrict__ outw_bf, unsigned short* __restrict__ y) {
  __shared__ float Hl[4][CCH][DSTATE];  // 16 KB
  __shared__ float Sl[4][CCH];          // 1 KB

  const int tid = threadIdx.x;
  const int c = tid & 3;
  const int k = tid >> 2;          // chunk 0..63
  const int b = blockIdx.y;
  const int i = blockIdx.x * 4 + c;
  const int n0 = b * SEQLEN + k * CT;

  const float dtw = dt_w[i], dtb = dt_b[i];
  float Av[DSTATE];
#pragma unroll
  for (int s = 0; s < DSTATE; ++s) Av[s] = -__expf(A_log[i * DSTATE + s]);

  // ---- phase 1: local chunk scan from h=0
  float h[DSTATE] = {};
  float Ssum = 0.f;
  for (int t = 0; t < CT; ++t) {
    const float* pr = proj + (size_t)(n0 + t) * PSTRIDE;
    float fr[20];
#pragma unroll
    for (int j = 0; j < 5; ++j) {
      const float4 v = *(const float4*)(pr + j * 4);
      fr[4 * j + 0] = v.x; fr[4 * j + 1] = v.y;
      fr[4 * j + 2] = v.z; fr[4 * j + 3] = v.w;
    }
    const float delta = 1.f + __expf(fmaf(fr[0], dtw, dtb));
    Ssum += delta;
    const float x = xg[(size_t)(n0 + t) * DINNER + i];
    const float dx = delta * x;
#pragma unroll
    for (int s = 0; s < DSTATE; ++s)
      h[s] = fmaf(__expf(Av[s] * delta), h[s], fr[1 + s] * dx);
  }
  Sl[c][k] = Ssum;
#pragma unroll
  for (int s = 0; s < DSTATE; ++s) Hl[c][k][s] = h[s];
  __syncthreads();

  // ---- phase 2: cross-chunk compose (64 threads) + out-zero/cast (192)
  if (tid < 64) {
    const int cc = tid & 3;
    const int s = tid >> 2;
    const float Av2 = -__expf(A_log[(blockIdx.x * 4 + cc) * DSTATE + s]);
    float H = 0.f;
#pragma unroll 4
    for (int k2 = 0; k2 < CCH; ++k2) {
      const float hk = Hl[cc][k2][s];
      const float a = __expf(Av2 * Sl[cc][k2]);
      Hl[cc][k2][s] = H;
      H = fmaf(a, H, hk);
    }
  } else {
    const int gid = (b * 512 + blockIdx.x) * 192 + (tid - 64);  // < 196608
    const float4 z4 = make_float4(0.f, 0.f, 0.f, 0.f);
    for (int j = gid; j < (NTOK * DMODEL) / 4; j += 196608)
      ((float4*)out)[j] = z4;
    for (int j = gid; j < (DMODEL * DINNER) / 8; j += 196608) {
      const float4 a = *(const float4*)(out_w + j * 8);
      const float4 bq = *(const float4*)(out_w + j * 8 + 4);
      us8 o;
      o[0] = f2bf(a.x); o[1] = f2bf(a.y); o[2] = f2bf(a.z); o[3] = f2bf(a.w);
      o[4] = f2bf(bq.x); o[5] = f2bf(bq.y); o[6] = f2bf(bq.z); o[7] = f2bf(bq.w);
      *(us8*)(outw_bf + j * 8) = o;
    }
  }
  __syncthreads();

  // ---- phase 3: re-scan seeded with h0 (from LDS), emit y
  const float Dv = Dp[i];
#pragma unroll
  for (int s = 0; s < DSTATE; ++s) h[s] = Hl[c][k][s];
  for (int t = 0; t < CT; ++t) {
    const float* pr = proj + (size_t)(n0 + t) * PSTRIDE;
    float fr[36];
#pragma unroll
    for (int j = 0; j < 9; ++j) {
      const float4 v = *(const float4*)(pr + j * 4);
      fr[4 * j + 0] = v.x; fr[4 * j + 1] = v.y;
      fr[4 * j + 2] = v.z; fr[4 * j + 3] = v.w;
    }
    const float delta = 1.f + __expf(fmaf(fr[0], dtw, dtb));
    const float x = xg[(size_t)(n0 + t) * DINNER + i];
    const float dx = delta * x;
    float yt = 0.f;
#pragma unroll
    for (int s = 0; s < DSTATE; ++s) {
      h[s] = fmaf(__expf(Av[s] * delta), h[s], fr[1 + s] * dx);
      yt = fmaf(h[s], fr[17 + s], yt);
    }
    y[(size_t)(n0 + t) * DINNER + i] = f2bf(fmaf(Dv, x, yt));
  }
}

// ---------------------------------------------------------------------------
extern "C" void kernel_launch(void* const* d_in, const int* in_sizes, int n_in,
                              void* d_out, int out_size, void* d_ws, size_t ws_size,
                              hipStream_t stream) {
  const float* x       = (const float*)d_in[0];
  const float* in_w    = (const float*)d_in[1];
  const float* in_b    = (const float*)d_in[2];
  const float* conv_w  = (const float*)d_in[3];
  const float* conv_b  = (const float*)d_in[4];
  const float* xproj_w = (const float*)d_in[5];
  const float* dt_w    = (const float*)d_in[6];
  const float* dt_b    = (const float*)d_in[7];
  const float* A_log   = (const float*)d_in[8];
  const float* Dp      = (const float*)d_in[9];
  const float* out_w   = (const float*)d_in[10];
  float* out = (float*)d_out;

  // Workspace (float offsets), fully disjoint:
  //   xz_bf   @ 0          8M bf16 (4M floats)   gemm1 -> conv_xproj
  //   xg      @ 8388608    4M      conv_xproj -> scan
  //   casts   @ 12582912   x_bf|inw_bf|wpad_bf|outw_bf (8486912 bf16)
  //   yb_bf   @ 16826368   2M      scan -> gemm2 (4M bf16)
  //   proj36  @ 18923520   73728   conv_xproj(atomic) -> scan
  float* ws = (float*)d_ws;
  unsigned short* xz_bf = (unsigned short*)ws;
  float* xg = ws + 8388608;
  unsigned short* bf_base = (unsigned short*)(ws + 12582912);
  unsigned short* x_bf    = bf_base;
  unsigned short* inw_bf  = bf_base + CAST_N0;
  unsigned short* wpad_bf = bf_base + CAST_N1;
  unsigned short* outw_bf = bf_base + CAST_N2;
  unsigned short* yb_bf = (unsigned short*)(ws + 16826368);
  float* proj = ws + 18923520;

  // 1. fused bf16 cast of x/in_w/xproj_w (+ proj36 zeroing)
  cast3_bf16_kernel<<<CAST_N2 / (256 * 8), 256, 0, stream>>>(
      x, in_w, xproj_w, bf_base, proj);

  // 2. in-projection: xz_bf = bf16(x @ in_w.T + in_b)   (2048 x 4096, K=1024)
  gemm_bt_mfma<<<dim3(NTOK / 128, (2 * DINNER) / 128), 256, 0, stream>>>(
      x_bf, inw_bf, in_b, xz_bf, 2 * DINNER, DMODEL);

  // 3. fused conv + SiLU + xproj (atomic k-split) -> xg, proj36
  conv_xproj_mfma<<<dim3(NTOK / 64, DINNER / 128), 256, 0, stream>>>(
      xz_bf, conv_w, conv_b, wpad_bf, xg, proj);

  // 4. fully fused scan (also zeroes `out`, casts out_w) -> yb_bf
  scan_fused<<<dim3(DINNER / 4, 2), 256, 0, stream>>>(
      xg, proj, dt_w, dt_b, A_log, Dp, out, out_w, outw_bf, yb_bf);

  // 5. out-projection (split-K=2, atomic into zeroed out)
  gemm_bt_mfma_sk<<<dim3(NTOK / 128, DMODEL / 64, 2), 256, 0, stream>>>(
      yb_bf, outw_bf, out, DMODEL, DINNER);
}

// Round 13
// 212.685 us; speedup vs baseline: 1.0457x; 1.0457x over previous
//
#include <hip/hip_runtime.h>
#include <hip/hip_bf16.h>

// Problem shapes (fixed by setup_inputs):
//   b=2, L=1024, d_model=1024, d_inner=2048, d_state=16, D_CONV=4
#define NTOK   2048
#define DMODEL 1024
#define DINNER 2048
#define DSTATE 16
#define SEQLEN 1024
#define NPROJ  33   // 2*d_state + 1
#define NPAD   48   // NPROJ padded for MFMA tiles
#define CCH    64   // scan chunks per sequence
#define CT     16   // steps per chunk

typedef __attribute__((ext_vector_type(8))) short bf16x8;
typedef __attribute__((ext_vector_type(4))) float f32x4;
typedef __attribute__((ext_vector_type(8))) unsigned short us8;

__device__ __forceinline__ unsigned short f2bf(float f) {
  unsigned u = __float_as_uint(f);
  return (unsigned short)((u + 0x7FFFu + ((u >> 16) & 1u)) >> 16);  // RNE
}
__device__ __forceinline__ float bf2f(unsigned short u) {
  return __uint_as_float(((unsigned)u) << 16);
}

__device__ __forceinline__ void gload_lds16(const void* g, void* l) {
  __builtin_amdgcn_global_load_lds(
      (const __attribute__((address_space(1))) unsigned int*)g,
      (__attribute__((address_space(3))) unsigned int*)l, 16, 0, 0);
}

// ---------------------------------------------------------------------------
// Fused fp32->bf16 cast: x (2M) | in_w (4M) | xproj_w padded to 48x2048.
// Blocks 0..32 additionally zero proj (2048 x 33 floats) for conv_xproj's
// atomicAdd epilogue.
// ---------------------------------------------------------------------------
#define CAST_N0 (NTOK * DMODEL)                       // 2097152
#define CAST_N1 (CAST_N0 + 2 * DINNER * DMODEL)       // 6291456
#define CAST_N2 (CAST_N1 + NPAD * DINNER)             // 6389760
__global__ __launch_bounds__(256) void cast3_bf16_kernel(
    const float* __restrict__ s0, const float* __restrict__ s1,
    const float* __restrict__ s3, unsigned short* __restrict__ dst,
    float* __restrict__ proj) {
  if (blockIdx.x < 33) {
    const int o = blockIdx.x * 2048 + threadIdx.x * 8;
    const float4 z4 = make_float4(0.f, 0.f, 0.f, 0.f);
    *(float4*)(proj + o) = z4;
    *(float4*)(proj + o + 4) = z4;
  }
  const int idx = (blockIdx.x * 256 + threadIdx.x) * 8;
  const float* src;
  int off;
  if (idx < CAST_N0) { src = s0; off = idx; }
  else if (idx < CAST_N1) { src = s1; off = idx - CAST_N0; }
  else {
    off = idx - CAST_N1;
    if (off >= NPROJ * DINNER) {  // zero pad rows 33..47
      us8 z = {0, 0, 0, 0, 0, 0, 0, 0};
      *(us8*)(dst + idx) = z;
      return;
    }
    src = s3;
  }
  const float4 a = *(const float4*)(src + off);
  const float4 b = *(const float4*)(src + off + 4);
  us8 o;
  o[0] = f2bf(a.x); o[1] = f2bf(a.y); o[2] = f2bf(a.z); o[3] = f2bf(a.w);
  o[4] = f2bf(b.x); o[5] = f2bf(b.y); o[6] = f2bf(b.z); o[7] = f2bf(b.w);
  *(us8*)(dst + idx) = o;
}

// ---------------------------------------------------------------------------
// bf16 MFMA GEMM (gemm1): C_bf16[n,m] = f2bf(sum_k A[n,k]*B[m,k] + bias[m]).
// Block tile 128x128; K advances 64 per barrier pair (two 32-deep stages).
// ---------------------------------------------------------------------------
__global__ __launch_bounds__(256) void gemm_bt_mfma(
    const unsigned short* __restrict__ A, const unsigned short* __restrict__ B,
    const float* __restrict__ bias, unsigned short* __restrict__ C,
    int M, int K) {
  constexpr int BN = 128, TN = 4;
  __shared__ unsigned short As[2][128 * 32];
  __shared__ unsigned short Bs[2][BN * 32];

  const int tid = threadIdx.x;
  const int wid = tid >> 6;
  const int lane = tid & 63;
  const int n0 = blockIdx.x * 128;
  const int m0 = blockIdx.y * BN;

  const int wave_m = wid & 1;
  const int wave_n = wid >> 1;
  const int lm = lane & 15;
  const int lq = lane >> 4;

  f32x4 acc[4][TN] = {};

  for (int k0 = 0; k0 < K; k0 += 64) {
    __syncthreads();
#pragma unroll
    for (int h = 0; h < 2; ++h) {
      const int kh = k0 + h * 32;
#pragma unroll
      for (int j = 0; j < 2; ++j) {
        const int cb = j * 256 + wid * 64;
        const int c = cb + lane;
        gload_lds16(A + (size_t)(n0 + (c >> 2)) * K + kh + (c & 3) * 8,
                    &As[h][cb * 8]);
      }
#pragma unroll
      for (int j = 0; j < BN / 64; ++j) {
        const int cb = j * 256 + wid * 64;
        const int c = cb + lane;
        gload_lds16(B + (size_t)(m0 + (c >> 2)) * K + kh + (c & 3) * 8,
                    &Bs[h][cb * 8]);
      }
    }
    __syncthreads();

#pragma unroll
    for (int h = 0; h < 2; ++h) {
      bf16x8 af[4], bfr[TN];
#pragma unroll
      for (int tm = 0; tm < 4; ++tm)
        af[tm] = *(const bf16x8*)
            &As[h][(wave_m * 64 + tm * 16 + lm) * 32 + lq * 8];
#pragma unroll
      for (int tn = 0; tn < TN; ++tn)
        bfr[tn] = *(const bf16x8*)
            &Bs[h][(wave_n * (BN / 2) + tn * 16 + lm) * 32 + lq * 8];
#pragma unroll
      for (int tm = 0; tm < 4; ++tm)
#pragma unroll
        for (int tn = 0; tn < TN; ++tn)
          acc[tm][tn] = __builtin_amdgcn_mfma_f32_16x16x32_bf16(
              af[tm], bfr[tn], acc[tm][tn], 0, 0, 0);
    }
  }

#pragma unroll
  for (int tm = 0; tm < 4; ++tm) {
    const int row = n0 + wave_m * 64 + tm * 16 + lq * 4;
#pragma unroll
    for (int tn = 0; tn < TN; ++tn) {
      const int col = m0 + wave_n * (BN / 2) + tn * 16 + lm;
      const float bv = bias[col];
#pragma unroll
      for (int r = 0; r < 4; ++r)
        C[(size_t)(row + r) * M + col] = f2bf(acc[tm][tn][r] + bv);
    }
  }
}

// ---------------------------------------------------------------------------
// gemm2 with split-K=2 and atomicAdd epilogue (out zeroed by scan_phase2).
// Block tile 128x64; grid (16, 16, 2).
// ---------------------------------------------------------------------------
__global__ __launch_bounds__(256) void gemm_bt_mfma_sk(
    const unsigned short* __restrict__ A, const unsigned short* __restrict__ B,
    float* __restrict__ C, int M, int K) {
  constexpr int BN = 64, TN = 2;
  __shared__ unsigned short As[2][128 * 32];
  __shared__ unsigned short Bs[2][BN * 32];

  const int tid = threadIdx.x;
  const int wid = tid >> 6;
  const int lane = tid & 63;
  const int n0 = blockIdx.x * 128;
  const int m0 = blockIdx.y * BN;
  const int kstart = blockIdx.z * (K >> 1);

  const int wave_m = wid & 1;
  const int wave_n = wid >> 1;
  const int lm = lane & 15;
  const int lq = lane >> 4;

  f32x4 acc[4][TN] = {};

  for (int k0 = kstart; k0 < kstart + (K >> 1); k0 += 64) {
    __syncthreads();
#pragma unroll
    for (int h = 0; h < 2; ++h) {
      const int kh = k0 + h * 32;
#pragma unroll
      for (int j = 0; j < 2; ++j) {
        const int cb = j * 256 + wid * 64;
        const int c = cb + lane;
        gload_lds16(A + (size_t)(n0 + (c >> 2)) * K + kh + (c & 3) * 8,
                    &As[h][cb * 8]);
      }
      {
        const int cb = wid * 64;
        const int c = cb + lane;
        gload_lds16(B + (size_t)(m0 + (c >> 2)) * K + kh + (c & 3) * 8,
                    &Bs[h][cb * 8]);
      }
    }
    __syncthreads();

#pragma unroll
    for (int h = 0; h < 2; ++h) {
      bf16x8 af[4], bfr[TN];
#pragma unroll
      for (int tm = 0; tm < 4; ++tm)
        af[tm] = *(const bf16x8*)
            &As[h][(wave_m * 64 + tm * 16 + lm) * 32 + lq * 8];
#pragma unroll
      for (int tn = 0; tn < TN; ++tn)
        bfr[tn] = *(const bf16x8*)
            &Bs[h][(wave_n * (BN / 2) + tn * 16 + lm) * 32 + lq * 8];
#pragma unroll
      for (int tm = 0; tm < 4; ++tm)
#pragma unroll
        for (int tn = 0; tn < TN; ++tn)
          acc[tm][tn] = __builtin_amdgcn_mfma_f32_16x16x32_bf16(
              af[tm], bfr[tn], acc[tm][tn], 0, 0, 0);
    }
  }

#pragma unroll
  for (int tm = 0; tm < 4; ++tm) {
    const int row = n0 + wave_m * 64 + tm * 16 + lq * 4;
#pragma unroll
    for (int tn = 0; tn < TN; ++tn) {
      const int col = m0 + wave_n * (BN / 2) + tn * 16 + lm;
#pragma unroll
      for (int r = 0; r < 4; ++r)
        atomicAdd(&C[(size_t)(row + r) * M + col], acc[tm][tn][r]);
    }
  }
}

// ---------------------------------------------------------------------------
// Fused depthwise conv(4) + SiLU gate + xproj MFMA with k-split atomics.
// xz is bf16; xg output is now bf16 too (scan reads it twice — halves that
// traffic; the MFMA path already used bf16 xg). Grid (32, 16) = 512 blocks.
// ---------------------------------------------------------------------------
__global__ __launch_bounds__(256) void conv_xproj_mfma(
    const unsigned short* __restrict__ xz, const float* __restrict__ cw,
    const float* __restrict__ cb, const unsigned short* __restrict__ wp,
    unsigned short* __restrict__ xgb, float* __restrict__ proj) {
  __shared__ unsigned short As[4][64 * 32];
  __shared__ unsigned short Bs[4][NPAD * 32];

  const int tid = threadIdx.x;
  const int wid = tid >> 6;
  const int lane = tid & 63;
  const int n0 = blockIdx.x * 64;    // token tile
  const int kb = blockIdx.y * 128;   // channel (k) tile

  // Phase A: B-tile staging, 768 x 16B chunks, stage-major dest.
#pragma unroll
  for (int j = 0; j < 3; ++j) {
    const int cbase = j * 256 + wid * 64;  // wave-uniform
    const int c = cbase + lane;
    const int stage = c / 192;
    const int rem = c - stage * 192;
    gload_lds16(wp + (size_t)(rem >> 2) * DINNER + kb + stage * 32 + (rem & 3) * 8,
                &Bs[0][0] + cbase * 8);
  }

  // Phase B: conv + SiLU. thread = chan c128, 32-token half.
  const int c128 = tid & 127;
  const int half = tid >> 7;
  const int i = kb + c128;
  const int gt0 = n0 + half * 32;
  const float4 w4 = ((const float4*)cw)[i];
  const float cbv = cb[i];

  const bool seq_start = ((gt0 & (SEQLEN - 1)) == 0);
  float tm3 = seq_start ? 0.f : bf2f(xz[(size_t)(gt0 - 3) * (2 * DINNER) + i]);
  float tm2 = seq_start ? 0.f : bf2f(xz[(size_t)(gt0 - 2) * (2 * DINNER) + i]);
  float tm1 = seq_start ? 0.f : bf2f(xz[(size_t)(gt0 - 1) * (2 * DINNER) + i]);

  unsigned short* Arow = &As[c128 >> 5][c128 & 31];
#pragma unroll 4
  for (int t = 0; t < 32; ++t) {
    const int n = gt0 + t;
    const float x0 = bf2f(xz[(size_t)n * (2 * DINNER) + i]);
    float acc = cbv;
    acc = fmaf(w4.x, tm3, acc);
    acc = fmaf(w4.y, tm2, acc);
    acc = fmaf(w4.z, tm1, acc);
    acc = fmaf(w4.w, x0, acc);
    const float z = bf2f(xz[(size_t)n * (2 * DINNER) + DINNER + i]);
    const float sig = 1.f / (1.f + __expf(-z));
    const float v = acc * (z * sig);
    const unsigned short vb = f2bf(v);
    xgb[(size_t)n * DINNER + i] = vb;
    Arow[(half * 32 + t) * 32] = vb;
    tm3 = tm2; tm2 = tm1; tm1 = x0;
  }
  __syncthreads();  // drains Bs vmcnt + As writes

  // Phase C: wave = tokens [wid*16, wid*16+16) x feats [0,48).
  const int lm = lane & 15;
  const int lq = lane >> 4;
  f32x4 acc[3] = {};
#pragma unroll
  for (int stage = 0; stage < 4; ++stage) {
    bf16x8 af = *(const bf16x8*)&As[stage][(wid * 16 + lm) * 32 + lq * 8];
#pragma unroll
    for (int tn = 0; tn < 3; ++tn) {
      bf16x8 bfr = *(const bf16x8*)&Bs[stage][(tn * 16 + lm) * 32 + lq * 8];
      acc[tn] = __builtin_amdgcn_mfma_f32_16x16x32_bf16(af, bfr, acc[tn], 0, 0, 0);
    }
  }

  const int row = n0 + wid * 16 + lq * 4;
#pragma unroll
  for (int tn = 0; tn < 3; ++tn) {
    const int col = tn * 16 + lm;
    if (col < NPROJ) {
#pragma unroll
      for (int r = 0; r < 4; ++r)
        atomicAdd(&proj[(size_t)(row + r) * NPROJ + col], acc[tn][r]);
    }
  }
}

// ---------------------------------------------------------------------------
// Chunked selective scan (delta = 1+exp(u) == exp(softplus(u)); chunk decay
// exp(Av*sum(delta)) since prod(exp) = exp(sum)). xg is bf16.
// ---------------------------------------------------------------------------
__global__ __launch_bounds__(256) void scan_phase1(
    const unsigned short* __restrict__ xgb, const float* __restrict__ proj,
    const float* __restrict__ dt_w, const float* __restrict__ dt_b,
    const float* __restrict__ A_log,
    float* __restrict__ Sbuf, float* __restrict__ Hbuf) {
  __shared__ float pl[CT][36];
  const int tid = threadIdx.x;
  const int i = blockIdx.x * 256 + tid;
  const int k = blockIdx.y;
  const int b = blockIdx.z;
  const int n0 = b * SEQLEN + k * CT;

  for (int e = tid; e < CT * NPROJ; e += 256) {
    const int t = e / NPROJ;
    const int c = e - t * NPROJ;
    pl[t][c] = proj[(size_t)(n0 + t) * NPROJ + c];
  }
  __syncthreads();

  const float dtw = dt_w[i], dtb = dt_b[i];
  float Av[DSTATE];
#pragma unroll
  for (int s = 0; s < DSTATE; ++s) Av[s] = -__expf(A_log[i * DSTATE + s]);

  float h[DSTATE] = {};
  float Ssum = 0.f;

  for (int t = 0; t < CT; ++t) {
    const float delta = 1.f + __expf(fmaf(pl[t][0], dtw, dtb));
    Ssum += delta;
    const float x = bf2f(xgb[(size_t)(n0 + t) * DINNER + i]);
    const float dx = delta * x;
#pragma unroll
    for (int s = 0; s < DSTATE; ++s)
      h[s] = fmaf(__expf(Av[s] * delta), h[s], pl[t][1 + s] * dx);
  }

  const size_t ck = (size_t)(b * CCH + k) * DINNER + i;
  Sbuf[ck] = Ssum;
  float4* Hq = (float4*)(Hbuf + ck * DSTATE);
#pragma unroll
  for (int q = 0; q < 4; ++q)
    Hq[q] = make_float4(h[4 * q], h[4 * q + 1], h[4 * q + 2], h[4 * q + 3]);
}

// phase2: cross-chunk compose; also zeroes `out` (2M floats) and casts out_w
// (2M) to bf16 for gemm2 — both hidden under the 64-step serial compose chain.
__global__ __launch_bounds__(256) void scan_phase2(
    const float* __restrict__ A_log, const float* __restrict__ Sbuf,
    float* __restrict__ Hbuf, float* __restrict__ out,
    const float* __restrict__ out_w, unsigned short* __restrict__ outw_bf) {
  const int gid = blockIdx.x * 256 + threadIdx.x;
  const float4 z4 = make_float4(0.f, 0.f, 0.f, 0.f);
#pragma unroll
  for (int j = 0; j < 8; ++j)
    *(float4*)(out + (size_t)(j * 65536 + gid) * 4) = z4;

  // out_w cast: 32 contiguous elems per thread
  {
    const int base = gid * 32;
#pragma unroll
    for (int q = 0; q < 4; ++q) {
      const float4 a = *(const float4*)(out_w + base + q * 8);
      const float4 b = *(const float4*)(out_w + base + q * 8 + 4);
      us8 o;
      o[0] = f2bf(a.x); o[1] = f2bf(a.y); o[2] = f2bf(a.z); o[3] = f2bf(a.w);
      o[4] = f2bf(b.x); o[5] = f2bf(b.y); o[6] = f2bf(b.z); o[7] = f2bf(b.w);
      *(us8*)(outw_bf + base + q * 8) = o;
    }
  }

  const int s = gid & (DSTATE - 1);
  const int i = (gid >> 4) & (DINNER - 1);
  const int b = gid >> 15;
  const float Av = -__expf(A_log[i * DSTATE + s]);
  float H = 0.f;
  for (int k = 0; k < CCH; ++k) {
    const size_t ck = (size_t)(b * CCH + k) * DINNER + i;
    const float hk = Hbuf[ck * DSTATE + s];
    const float a = __expf(Av * Sbuf[ck]);
    Hbuf[ck * DSTATE + s] = H;
    H = fmaf(a, H, hk);
  }
}

__global__ __launch_bounds__(256) void scan_phase3(
    const unsigned short* __restrict__ xgb, const float* __restrict__ proj,
    const float* __restrict__ dt_w, const float* __restrict__ dt_b,
    const float* __restrict__ A_log, const float* __restrict__ Dp,
    const float* __restrict__ Hbuf, unsigned short* __restrict__ y) {
  __shared__ float pl[CT][36];
  const int tid = threadIdx.x;
  const int i = blockIdx.x * 256 + tid;
  const int k = blockIdx.y;
  const int b = blockIdx.z;
  const int n0 = b * SEQLEN + k * CT;

  for (int e = tid; e < CT * NPROJ; e += 256) {
    const int t = e / NPROJ;
    const int c = e - t * NPROJ;
    pl[t][c] = proj[(size_t)(n0 + t) * NPROJ + c];
  }
  __syncthreads();

  const float dtw = dt_w[i], dtb = dt_b[i];
  const float Dv = Dp[i];
  float Av[DSTATE];
#pragma unroll
  for (int s = 0; s < DSTATE; ++s) Av[s] = -__expf(A_log[i * DSTATE + s]);

  const size_t ck = (size_t)(b * CCH + k) * DINNER + i;
  float h[DSTATE];
  const float4* Hq = (const float4*)(Hbuf + ck * DSTATE);
#pragma unroll
  for (int q = 0; q < 4; ++q) {
    const float4 v = Hq[q];
    h[4 * q + 0] = v.x; h[4 * q + 1] = v.y;
    h[4 * q + 2] = v.z; h[4 * q + 3] = v.w;
  }

  for (int t = 0; t < CT; ++t) {
    const float delta = 1.f + __expf(fmaf(pl[t][0], dtw, dtb));
    const float x = bf2f(xgb[(size_t)(n0 + t) * DINNER + i]);
    const float dx = delta * x;
    float yt = 0.f;
#pragma unroll
    for (int s = 0; s < DSTATE; ++s) {
      h[s] = fmaf(__expf(Av[s] * delta), h[s], pl[t][1 + s] * dx);
      yt = fmaf(h[s], pl[t][17 + s], yt);
    }
    y[(size_t)(n0 + t) * DINNER + i] = f2bf(fmaf(Dv, x, yt));
  }
}

// ---------------------------------------------------------------------------
extern "C" void kernel_launch(void* const* d_in, const int* in_sizes, int n_in,
                              void* d_out, int out_size, void* d_ws, size_t ws_size,
                              hipStream_t stream) {
  const float* x       = (const float*)d_in[0];
  const float* in_w    = (const float*)d_in[1];
  const float* in_b    = (const float*)d_in[2];
  const float* conv_w  = (const float*)d_in[3];
  const float* conv_b  = (const float*)d_in[4];
  const float* xproj_w = (const float*)d_in[5];
  const float* dt_w    = (const float*)d_in[6];
  const float* dt_b    = (const float*)d_in[7];
  const float* A_log   = (const float*)d_in[8];
  const float* Dp      = (const float*)d_in[9];
  const float* out_w   = (const float*)d_in[10];
  float* out = (float*)d_out;

  // Workspace (float offsets), fully disjoint:
  //   xz_bf   @ 0          8M bf16 (4M floats)   gemm1 -> conv_xproj
  //   xgb     @ 8388608    4M bf16 (2M floats)   conv_xproj -> scan
  //   casts   @ 12582912   x_bf|inw_bf|wpad_bf|outw_bf (8486912 bf16)
  //   yb_bf   @ 16826368   2M      scan -> gemm2 (4M bf16)
  //   proj    @ 18923520   67584   conv_xproj(atomic) -> scan
  //   Sbuf    @ 19005440   262144
  //   Hbuf    @ 19267584   4M
  float* ws = (float*)d_ws;
  unsigned short* xz_bf = (unsigned short*)ws;
  unsigned short* xgb = (unsigned short*)(ws + 8388608);
  unsigned short* bf_base = (unsigned short*)(ws + 12582912);
  unsigned short* x_bf    = bf_base;
  unsigned short* inw_bf  = bf_base + CAST_N0;
  unsigned short* wpad_bf = bf_base + CAST_N1;
  unsigned short* outw_bf = bf_base + CAST_N2;
  unsigned short* yb_bf = (unsigned short*)(ws + 16826368);
  float* proj = ws + 18923520;
  float* Sbuf = ws + 19005440;
  float* Hbuf = ws + 19267584;

  // 1. fused bf16 cast of x/in_w/xproj_w (+ proj zeroing)
  cast3_bf16_kernel<<<CAST_N2 / (256 * 8), 256, 0, stream>>>(
      x, in_w, xproj_w, bf_base, proj);

  // 2. in-projection: xz_bf = bf16(x @ in_w.T + in_b)   (2048 x 4096, K=1024)
  gemm_bt_mfma<<<dim3(NTOK / 128, (2 * DINNER) / 128), 256, 0, stream>>>(
      x_bf, inw_bf, in_b, xz_bf, 2 * DINNER, DMODEL);

  // 3. fused conv + SiLU + xproj (atomic k-split) -> xgb, proj
  conv_xproj_mfma<<<dim3(NTOK / 64, DINNER / 128), 256, 0, stream>>>(
      xz_bf, conv_w, conv_b, wpad_bf, xgb, proj);

  // 4. chunked selective scan -> yb_bf (phase2 zeroes `out`, casts out_w)
  scan_phase1<<<dim3(DINNER / 256, CCH, 2), 256, 0, stream>>>(
      xgb, proj, dt_w, dt_b, A_log, Sbuf, Hbuf);
  scan_phase2<<<(2 * DINNER * DSTATE) / 256, 256, 0, stream>>>(
      A_log, Sbuf, Hbuf, out, out_w, outw_bf);
  scan_phase3<<<dim3(DINNER / 256, CCH, 2), 256, 0, stream>>>(
      xgb, proj, dt_w, dt_b, A_log, Dp, Hbuf, yb_bf);

  // 5. out-projection (split-K=2, atomic into zeroed out)
  gemm_bt_mfma_sk<<<dim3(NTOK / 128, DMODEL / 64, 2), 256, 0, stream>>>(
      yb_bf, outw_bf, out, DMODEL, DINNER);
}

// Round 14
// 207.517 us; speedup vs baseline: 1.0718x; 1.0249x over previous
//
#include <hip/hip_runtime.h>
#include <hip/hip_bf16.h>

// Problem shapes (fixed by setup_inputs):
//   b=2, L=1024, d_model=1024, d_inner=2048, d_state=16, D_CONV=4
#define NTOK   2048
#define DMODEL 1024
#define DINNER 2048
#define DSTATE 16
#define SEQLEN 1024
#define NPROJ  33   // 2*d_state + 1
#define NPAD   48   // NPROJ padded for MFMA tiles
#define CCH    64   // scan chunks per sequence
#define CT     16   // steps per chunk

typedef __attribute__((ext_vector_type(8))) short bf16x8;
typedef __attribute__((ext_vector_type(4))) float f32x4;
typedef __attribute__((ext_vector_type(8))) unsigned short us8;

__device__ __forceinline__ unsigned short f2bf(float f) {
  unsigned u = __float_as_uint(f);
  return (unsigned short)((u + 0x7FFFu + ((u >> 16) & 1u)) >> 16);  // RNE
}
__device__ __forceinline__ float bf2f(unsigned short u) {
  return __uint_as_float(((unsigned)u) << 16);
}

__device__ __forceinline__ void gload_lds16(const void* g, void* l) {
  __builtin_amdgcn_global_load_lds(
      (const __attribute__((address_space(1))) unsigned int*)g,
      (__attribute__((address_space(3))) unsigned int*)l, 16, 0, 0);
}

// ---------------------------------------------------------------------------
// Fused fp32->bf16 cast: x (2M) | in_w (4M) | xproj_w padded to 48x2048.
// Blocks 0..32 additionally zero proj (2048 x 33 floats) for conv_xproj's
// atomicAdd epilogue.
// ---------------------------------------------------------------------------
#define CAST_N0 (NTOK * DMODEL)                       // 2097152
#define CAST_N1 (CAST_N0 + 2 * DINNER * DMODEL)       // 6291456
#define CAST_N2 (CAST_N1 + NPAD * DINNER)             // 6389760
__global__ __launch_bounds__(256) void cast3_bf16_kernel(
    const float* __restrict__ s0, const float* __restrict__ s1,
    const float* __restrict__ s3, unsigned short* __restrict__ dst,
    float* __restrict__ proj) {
  if (blockIdx.x < 33) {
    const int o = blockIdx.x * 2048 + threadIdx.x * 8;
    const float4 z4 = make_float4(0.f, 0.f, 0.f, 0.f);
    *(float4*)(proj + o) = z4;
    *(float4*)(proj + o + 4) = z4;
  }
  const int idx = (blockIdx.x * 256 + threadIdx.x) * 8;
  const float* src;
  int off;
  if (idx < CAST_N0) { src = s0; off = idx; }
  else if (idx < CAST_N1) { src = s1; off = idx - CAST_N0; }
  else {
    off = idx - CAST_N1;
    if (off >= NPROJ * DINNER) {  // zero pad rows 33..47
      us8 z = {0, 0, 0, 0, 0, 0, 0, 0};
      *(us8*)(dst + idx) = z;
      return;
    }
    src = s3;
  }
  const float4 a = *(const float4*)(src + off);
  const float4 b = *(const float4*)(src + off + 4);
  us8 o;
  o[0] = f2bf(a.x); o[1] = f2bf(a.y); o[2] = f2bf(a.z); o[3] = f2bf(a.w);
  o[4] = f2bf(b.x); o[5] = f2bf(b.y); o[6] = f2bf(b.z); o[7] = f2bf(b.w);
  *(us8*)(dst + idx) = o;
}

// ---------------------------------------------------------------------------
// bf16 MFMA GEMM (gemm1): C_bf16[n,m] = f2bf(sum_k A[n,k]*B[m,k] + bias[m]).
// Block tile 128x128; K advances 128 per barrier pair (FOUR 32-deep stages —
// halves barrier-drain count vs BK=64; occupancy stays 2 blocks/CU at 64 KB).
// ---------------------------------------------------------------------------
__global__ __launch_bounds__(256) void gemm_bt_mfma(
    const unsigned short* __restrict__ A, const unsigned short* __restrict__ B,
    const float* __restrict__ bias, unsigned short* __restrict__ C,
    int M, int K) {
  constexpr int BN = 128, TN = 4;
  __shared__ unsigned short As[4][128 * 32];
  __shared__ unsigned short Bs[4][BN * 32];

  const int tid = threadIdx.x;
  const int wid = tid >> 6;
  const int lane = tid & 63;
  const int n0 = blockIdx.x * 128;
  const int m0 = blockIdx.y * BN;

  const int wave_m = wid & 1;
  const int wave_n = wid >> 1;
  const int lm = lane & 15;
  const int lq = lane >> 4;

  f32x4 acc[4][TN] = {};

  for (int k0 = 0; k0 < K; k0 += 128) {
    __syncthreads();
#pragma unroll
    for (int h = 0; h < 4; ++h) {
      const int kh = k0 + h * 32;
#pragma unroll
      for (int j = 0; j < 2; ++j) {
        const int cb = j * 256 + wid * 64;
        const int c = cb + lane;
        gload_lds16(A + (size_t)(n0 + (c >> 2)) * K + kh + (c & 3) * 8,
                    &As[h][cb * 8]);
      }
#pragma unroll
      for (int j = 0; j < BN / 64; ++j) {
        const int cb = j * 256 + wid * 64;
        const int c = cb + lane;
        gload_lds16(B + (size_t)(m0 + (c >> 2)) * K + kh + (c & 3) * 8,
                    &Bs[h][cb * 8]);
      }
    }
    __syncthreads();

#pragma unroll
    for (int h = 0; h < 4; ++h) {
      bf16x8 af[4], bfr[TN];
#pragma unroll
      for (int tm = 0; tm < 4; ++tm)
        af[tm] = *(const bf16x8*)
            &As[h][(wave_m * 64 + tm * 16 + lm) * 32 + lq * 8];
#pragma unroll
      for (int tn = 0; tn < TN; ++tn)
        bfr[tn] = *(const bf16x8*)
            &Bs[h][(wave_n * (BN / 2) + tn * 16 + lm) * 32 + lq * 8];
#pragma unroll
      for (int tm = 0; tm < 4; ++tm)
#pragma unroll
        for (int tn = 0; tn < TN; ++tn)
          acc[tm][tn] = __builtin_amdgcn_mfma_f32_16x16x32_bf16(
              af[tm], bfr[tn], acc[tm][tn], 0, 0, 0);
    }
  }

#pragma unroll
  for (int tm = 0; tm < 4; ++tm) {
    const int row = n0 + wave_m * 64 + tm * 16 + lq * 4;
#pragma unroll
    for (int tn = 0; tn < TN; ++tn) {
      const int col = m0 + wave_n * (BN / 2) + tn * 16 + lm;
      const float bv = bias[col];
#pragma unroll
      for (int r = 0; r < 4; ++r)
        C[(size_t)(row + r) * M + col] = f2bf(acc[tm][tn][r] + bv);
    }
  }
}

// ---------------------------------------------------------------------------
// gemm2 with split-K=2 and atomicAdd epilogue (out zeroed by scan_phase2).
// Block tile 128x64; K advances 128 per barrier pair (four 32-deep stages).
// Grid (16, 16, 2); LDS 48 KB -> 3 blocks/CU.
// ---------------------------------------------------------------------------
__global__ __launch_bounds__(256) void gemm_bt_mfma_sk(
    const unsigned short* __restrict__ A, const unsigned short* __restrict__ B,
    float* __restrict__ C, int M, int K) {
  constexpr int BN = 64, TN = 2;
  __shared__ unsigned short As[4][128 * 32];
  __shared__ unsigned short Bs[4][BN * 32];

  const int tid = threadIdx.x;
  const int wid = tid >> 6;
  const int lane = tid & 63;
  const int n0 = blockIdx.x * 128;
  const int m0 = blockIdx.y * BN;
  const int kstart = blockIdx.z * (K >> 1);

  const int wave_m = wid & 1;
  const int wave_n = wid >> 1;
  const int lm = lane & 15;
  const int lq = lane >> 4;

  f32x4 acc[4][TN] = {};

  for (int k0 = kstart; k0 < kstart + (K >> 1); k0 += 128) {
    __syncthreads();
#pragma unroll
    for (int h = 0; h < 4; ++h) {
      const int kh = k0 + h * 32;
#pragma unroll
      for (int j = 0; j < 2; ++j) {
        const int cb = j * 256 + wid * 64;
        const int c = cb + lane;
        gload_lds16(A + (size_t)(n0 + (c >> 2)) * K + kh + (c & 3) * 8,
                    &As[h][cb * 8]);
      }
      {
        const int cb = wid * 64;
        const int c = cb + lane;
        gload_lds16(B + (size_t)(m0 + (c >> 2)) * K + kh + (c & 3) * 8,
                    &Bs[h][cb * 8]);
      }
    }
    __syncthreads();

#pragma unroll
    for (int h = 0; h < 4; ++h) {
      bf16x8 af[4], bfr[TN];
#pragma unroll
      for (int tm = 0; tm < 4; ++tm)
        af[tm] = *(const bf16x8*)
            &As[h][(wave_m * 64 + tm * 16 + lm) * 32 + lq * 8];
#pragma unroll
      for (int tn = 0; tn < TN; ++tn)
        bfr[tn] = *(const bf16x8*)
            &Bs[h][(wave_n * (BN / 2) + tn * 16 + lm) * 32 + lq * 8];
#pragma unroll
      for (int tm = 0; tm < 4; ++tm)
#pragma unroll
        for (int tn = 0; tn < TN; ++tn)
          acc[tm][tn] = __builtin_amdgcn_mfma_f32_16x16x32_bf16(
              af[tm], bfr[tn], acc[tm][tn], 0, 0, 0);
    }
  }

#pragma unroll
  for (int tm = 0; tm < 4; ++tm) {
    const int row = n0 + wave_m * 64 + tm * 16 + lq * 4;
#pragma unroll
    for (int tn = 0; tn < TN; ++tn) {
      const int col = m0 + wave_n * (BN / 2) + tn * 16 + lm;
#pragma unroll
      for (int r = 0; r < 4; ++r)
        atomicAdd(&C[(size_t)(row + r) * M + col], acc[tm][tn][r]);
    }
  }
}

// ---------------------------------------------------------------------------
// Fused depthwise conv(4) + SiLU gate + xproj MFMA with k-split atomics.
// xz is bf16; xg output bf16. Grid (32, 16) = 512 blocks.
// ---------------------------------------------------------------------------
__global__ __launch_bounds__(256) void conv_xproj_mfma(
    const unsigned short* __restrict__ xz, const float* __restrict__ cw,
    const float* __restrict__ cb, const unsigned short* __restrict__ wp,
    unsigned short* __restrict__ xgb, float* __restrict__ proj) {
  __shared__ unsigned short As[4][64 * 32];
  __shared__ unsigned short Bs[4][NPAD * 32];

  const int tid = threadIdx.x;
  const int wid = tid >> 6;
  const int lane = tid & 63;
  const int n0 = blockIdx.x * 64;    // token tile
  const int kb = blockIdx.y * 128;   // channel (k) tile

  // Phase A: B-tile staging, 768 x 16B chunks, stage-major dest.
#pragma unroll
  for (int j = 0; j < 3; ++j) {
    const int cbase = j * 256 + wid * 64;  // wave-uniform
    const int c = cbase + lane;
    const int stage = c / 192;
    const int rem = c - stage * 192;
    gload_lds16(wp + (size_t)(rem >> 2) * DINNER + kb + stage * 32 + (rem & 3) * 8,
                &Bs[0][0] + cbase * 8);
  }

  // Phase B: conv + SiLU. thread = chan c128, 32-token half.
  const int c128 = tid & 127;
  const int half = tid >> 7;
  const int i = kb + c128;
  const int gt0 = n0 + half * 32;
  const float4 w4 = ((const float4*)cw)[i];
  const float cbv = cb[i];

  const bool seq_start = ((gt0 & (SEQLEN - 1)) == 0);
  float tm3 = seq_start ? 0.f : bf2f(xz[(size_t)(gt0 - 3) * (2 * DINNER) + i]);
  float tm2 = seq_start ? 0.f : bf2f(xz[(size_t)(gt0 - 2) * (2 * DINNER) + i]);
  float tm1 = seq_start ? 0.f : bf2f(xz[(size_t)(gt0 - 1) * (2 * DINNER) + i]);

  unsigned short* Arow = &As[c128 >> 5][c128 & 31];
#pragma unroll 4
  for (int t = 0; t < 32; ++t) {
    const int n = gt0 + t;
    const float x0 = bf2f(xz[(size_t)n * (2 * DINNER) + i]);
    float acc = cbv;
    acc = fmaf(w4.x, tm3, acc);
    acc = fmaf(w4.y, tm2, acc);
    acc = fmaf(w4.z, tm1, acc);
    acc = fmaf(w4.w, x0, acc);
    const float z = bf2f(xz[(size_t)n * (2 * DINNER) + DINNER + i]);
    const float sig = 1.f / (1.f + __expf(-z));
    const float v = acc * (z * sig);
    const unsigned short vb = f2bf(v);
    xgb[(size_t)n * DINNER + i] = vb;
    Arow[(half * 32 + t) * 32] = vb;
    tm3 = tm2; tm2 = tm1; tm1 = x0;
  }
  __syncthreads();  // drains Bs vmcnt + As writes

  // Phase C: wave = tokens [wid*16, wid*16+16) x feats [0,48).
  const int lm = lane & 15;
  const int lq = lane >> 4;
  f32x4 acc[3] = {};
#pragma unroll
  for (int stage = 0; stage < 4; ++stage) {
    bf16x8 af = *(const bf16x8*)&As[stage][(wid * 16 + lm) * 32 + lq * 8];
#pragma unroll
    for (int tn = 0; tn < 3; ++tn) {
      bf16x8 bfr = *(const bf16x8*)&Bs[stage][(tn * 16 + lm) * 32 + lq * 8];
      acc[tn] = __builtin_amdgcn_mfma_f32_16x16x32_bf16(af, bfr, acc[tn], 0, 0, 0);
    }
  }

  const int row = n0 + wid * 16 + lq * 4;
#pragma unroll
  for (int tn = 0; tn < 3; ++tn) {
    const int col = tn * 16 + lm;
    if (col < NPROJ) {
#pragma unroll
      for (int r = 0; r < 4; ++r)
        atomicAdd(&proj[(size_t)(row + r) * NPROJ + col], acc[tn][r]);
    }
  }
}

// ---------------------------------------------------------------------------
// Chunked selective scan (delta = 1+exp(u) == exp(softplus(u)); chunk decay
// exp(Av*sum(delta)) since prod(exp) = exp(sum)). xg is bf16.
// ---------------------------------------------------------------------------
__global__ __launch_bounds__(256) void scan_phase1(
    const unsigned short* __restrict__ xgb, const float* __restrict__ proj,
    const float* __restrict__ dt_w, const float* __restrict__ dt_b,
    const float* __restrict__ A_log,
    float* __restrict__ Sbuf, float* __restrict__ Hbuf) {
  __shared__ float pl[CT][36];
  const int tid = threadIdx.x;
  const int i = blockIdx.x * 256 + tid;
  const int k = blockIdx.y;
  const int b = blockIdx.z;
  const int n0 = b * SEQLEN + k * CT;

  for (int e = tid; e < CT * NPROJ; e += 256) {
    const int t = e / NPROJ;
    const int c = e - t * NPROJ;
    pl[t][c] = proj[(size_t)(n0 + t) * NPROJ + c];
  }
  __syncthreads();

  const float dtw = dt_w[i], dtb = dt_b[i];
  float Av[DSTATE];
#pragma unroll
  for (int s = 0; s < DSTATE; ++s) Av[s] = -__expf(A_log[i * DSTATE + s]);

  float h[DSTATE] = {};
  float Ssum = 0.f;

  for (int t = 0; t < CT; ++t) {
    const float delta = 1.f + __expf(fmaf(pl[t][0], dtw, dtb));
    Ssum += delta;
    const float x = bf2f(xgb[(size_t)(n0 + t) * DINNER + i]);
    const float dx = delta * x;
#pragma unroll
    for (int s = 0; s < DSTATE; ++s)
      h[s] = fmaf(__expf(Av[s] * delta), h[s], pl[t][1 + s] * dx);
  }

  const size_t ck = (size_t)(b * CCH + k) * DINNER + i;
  Sbuf[ck] = Ssum;
  float4* Hq = (float4*)(Hbuf + ck * DSTATE);
#pragma unroll
  for (int q = 0; q < 4; ++q)
    Hq[q] = make_float4(h[4 * q], h[4 * q + 1], h[4 * q + 2], h[4 * q + 3]);
}

// phase2: cross-chunk compose; also zeroes `out` (2M floats) and casts out_w
// (2M) to bf16 for gemm2 — both hidden under the 64-step serial compose chain.
__global__ __launch_bounds__(256) void scan_phase2(
    const float* __restrict__ A_log, const float* __restrict__ Sbuf,
    float* __restrict__ Hbuf, float* __restrict__ out,
    const float* __restrict__ out_w, unsigned short* __restrict__ outw_bf) {
  const int gid = blockIdx.x * 256 + threadIdx.x;
  const float4 z4 = make_float4(0.f, 0.f, 0.f, 0.f);
#pragma unroll
  for (int j = 0; j < 8; ++j)
    *(float4*)(out + (size_t)(j * 65536 + gid) * 4) = z4;

  // out_w cast: 32 contiguous elems per thread
  {
    const int base = gid * 32;
#pragma unroll
    for (int q = 0; q < 4; ++q) {
      const float4 a = *(const float4*)(out_w + base + q * 8);
      const float4 b = *(const float4*)(out_w + base + q * 8 + 4);
      us8 o;
      o[0] = f2bf(a.x); o[1] = f2bf(a.y); o[2] = f2bf(a.z); o[3] = f2bf(a.w);
      o[4] = f2bf(b.x); o[5] = f2bf(b.y); o[6] = f2bf(b.z); o[7] = f2bf(b.w);
      *(us8*)(outw_bf + base + q * 8) = o;
    }
  }

  const int s = gid & (DSTATE - 1);
  const int i = (gid >> 4) & (DINNER - 1);
  const int b = gid >> 15;
  const float Av = -__expf(A_log[i * DSTATE + s]);
  float H = 0.f;
  for (int k = 0; k < CCH; ++k) {
    const size_t ck = (size_t)(b * CCH + k) * DINNER + i;
    const float hk = Hbuf[ck * DSTATE + s];
    const float a = __expf(Av * Sbuf[ck]);
    Hbuf[ck * DSTATE + s] = H;
    H = fmaf(a, H, hk);
  }
}

__global__ __launch_bounds__(256) void scan_phase3(
    const unsigned short* __restrict__ xgb, const float* __restrict__ proj,
    const float* __restrict__ dt_w, const float* __restrict__ dt_b,
    const float* __restrict__ A_log, const float* __restrict__ Dp,
    const float* __restrict__ Hbuf, unsigned short* __restrict__ y) {
  __shared__ float pl[CT][36];
  const int tid = threadIdx.x;
  const int i = blockIdx.x * 256 + tid;
  const int k = blockIdx.y;
  const int b = blockIdx.z;
  const int n0 = b * SEQLEN + k * CT;

  for (int e = tid; e < CT * NPROJ; e += 256) {
    const int t = e / NPROJ;
    const int c = e - t * NPROJ;
    pl[t][c] = proj[(size_t)(n0 + t) * NPROJ + c];
  }
  __syncthreads();

  const float dtw = dt_w[i], dtb = dt_b[i];
  const float Dv = Dp[i];
  float Av[DSTATE];
#pragma unroll
  for (int s = 0; s < DSTATE; ++s) Av[s] = -__expf(A_log[i * DSTATE + s]);

  const size_t ck = (size_t)(b * CCH + k) * DINNER + i;
  float h[DSTATE];
  const float4* Hq = (const float4*)(Hbuf + ck * DSTATE);
#pragma unroll
  for (int q = 0; q < 4; ++q) {
    const float4 v = Hq[q];
    h[4 * q + 0] = v.x; h[4 * q + 1] = v.y;
    h[4 * q + 2] = v.z; h[4 * q + 3] = v.w;
  }

  for (int t = 0; t < CT; ++t) {
    const float delta = 1.f + __expf(fmaf(pl[t][0], dtw, dtb));
    const float x = bf2f(xgb[(size_t)(n0 + t) * DINNER + i]);
    const float dx = delta * x;
    float yt = 0.f;
#pragma unroll
    for (int s = 0; s < DSTATE; ++s) {
      h[s] = fmaf(__expf(Av[s] * delta), h[s], pl[t][1 + s] * dx);
      yt = fmaf(h[s], pl[t][17 + s], yt);
    }
    y[(size_t)(n0 + t) * DINNER + i] = f2bf(fmaf(Dv, x, yt));
  }
}

// ---------------------------------------------------------------------------
extern "C" void kernel_launch(void* const* d_in, const int* in_sizes, int n_in,
                              void* d_out, int out_size, void* d_ws, size_t ws_size,
                              hipStream_t stream) {
  const float* x       = (const float*)d_in[0];
  const float* in_w    = (const float*)d_in[1];
  const float* in_b    = (const float*)d_in[2];
  const float* conv_w  = (const float*)d_in[3];
  const float* conv_b  = (const float*)d_in[4];
  const float* xproj_w = (const float*)d_in[5];
  const float* dt_w    = (const float*)d_in[6];
  const float* dt_b    = (const float*)d_in[7];
  const float* A_log   = (const float*)d_in[8];
  const float* Dp      = (const float*)d_in[9];
  const float* out_w   = (const float*)d_in[10];
  float* out = (float*)d_out;

  // Workspace (float offsets), fully disjoint:
  //   xz_bf   @ 0          8M bf16 (4M floats)   gemm1 -> conv_xproj
  //   xgb     @ 8388608    4M bf16 (2M floats)   conv_xproj -> scan
  //   casts   @ 12582912   x_bf|inw_bf|wpad_bf|outw_bf (8486912 bf16)
  //   yb_bf   @ 16826368   2M      scan -> gemm2 (4M bf16)
  //   proj    @ 18923520   67584   conv_xproj(atomic) -> scan
  //   Sbuf    @ 19005440   262144
  //   Hbuf    @ 19267584   4M
  float* ws = (float*)d_ws;
  unsigned short* xz_bf = (unsigned short*)ws;
  unsigned short* xgb = (unsigned short*)(ws + 8388608);
  unsigned short* bf_base = (unsigned short*)(ws + 12582912);
  unsigned short* x_bf    = bf_base;
  unsigned short* inw_bf  = bf_base + CAST_N0;
  unsigned short* wpad_bf = bf_base + CAST_N1;
  unsigned short* outw_bf = bf_base + CAST_N2;
  unsigned short* yb_bf = (unsigned short*)(ws + 16826368);
  float* proj = ws + 18923520;
  float* Sbuf = ws + 19005440;
  float* Hbuf = ws + 19267584;

  // 1. fused bf16 cast of x/in_w/xproj_w (+ proj zeroing)
  cast3_bf16_kernel<<<CAST_N2 / (256 * 8), 256, 0, stream>>>(
      x, in_w, xproj_w, bf_base, proj);

  // 2. in-projection: xz_bf = bf16(x @ in_w.T + in_b)   (2048 x 4096, K=1024)
  gemm_bt_mfma<<<dim3(NTOK / 128, (2 * DINNER) / 128), 256, 0, stream>>>(
      x_bf, inw_bf, in_b, xz_bf, 2 * DINNER, DMODEL);

  // 3. fused conv + SiLU + xproj (atomic k-split) -> xgb, proj
  conv_xproj_mfma<<<dim3(NTOK / 64, DINNER / 128), 256, 0, stream>>>(
      xz_bf, conv_w, conv_b, wpad_bf, xgb, proj);

  // 4. chunked selective scan -> yb_bf (phase2 zeroes `out`, casts out_w)
  scan_phase1<<<dim3(DINNER / 256, CCH, 2), 256, 0, stream>>>(
      xgb, proj, dt_w, dt_b, A_log, Sbuf, Hbuf);
  scan_phase2<<<(2 * DINNER * DSTATE) / 256, 256, 0, stream>>>(
      A_log, Sbuf, Hbuf, out, out_w, outw_bf);
  scan_phase3<<<dim3(DINNER / 256, CCH, 2), 256, 0, stream>>>(
      xgb, proj, dt_w, dt_b, A_log, Dp, Hbuf, yb_bf);

  // 5. out-projection (split-K=2, atomic into zeroed out)
  gemm_bt_mfma_sk<<<dim3(NTOK / 128, DMODEL / 64, 2), 256, 0, stream>>>(
      yb_bf, outw_bf, out, DMODEL, DINNER);
}